// Round 1
// baseline (765.439 us; speedup 1.0000x reference)
//
#include <hip/hip_runtime.h>
#include <hip/hip_bf16.h>
#include <stdint.h>

// Problem constants
#define S2   2048
#define DD   4096
#define NH   32
#define NKVH 8
#define HD2  128
// qkv buffer row width: 4096 (q) + 1024 (k) + 1024 (v)
#define QKVW 6144

typedef __bf16 bf16x8 __attribute__((ext_vector_type(8)));
typedef float  f32x4  __attribute__((ext_vector_type(4)));
typedef unsigned short u16x8 __attribute__((ext_vector_type(8)));
typedef unsigned short u16x4 __attribute__((ext_vector_type(4)));

__device__ __forceinline__ unsigned short f2b(float f) {
    unsigned int u = __builtin_bit_cast(unsigned int, f);
    unsigned int r = (u + 0x7FFFu + ((u >> 16) & 1u)) >> 16;   // RNE
    return (unsigned short)r;
}
__device__ __forceinline__ float b2f(unsigned short h) {
    unsigned int u = ((unsigned int)h) << 16;
    return __builtin_bit_cast(float, u);
}

// global -> LDS direct copy, 16B per lane. LDS dest is wave-uniform base + lane*16.
__device__ __forceinline__ void gload_lds16(const void* g, void* lds) {
    __builtin_amdgcn_global_load_lds(
        (const __attribute__((address_space(1))) void*)(uintptr_t)g,
        (__attribute__((address_space(3))) void*)(uint32_t)(uintptr_t)lds,
        16, 0, 0);
}

// ---------------------------------------------------------------------------
// 1) fp32 -> bf16 conversion for x, wq, wk, wv, wo (concatenated into ws)
//    element counts (in float4 groups of the 48M total): x 2M | wq 4M | wk 1M | wv 1M | wo 4M
// ---------------------------------------------------------------------------
__global__ void cvt_all(const float* __restrict__ x,  const float* __restrict__ wq,
                        const float* __restrict__ wk, const float* __restrict__ wv,
                        const float* __restrict__ wo, unsigned short* __restrict__ dst) {
    const long long NG = 12LL * 1024 * 1024;  // float4 groups
    const long long stride = (long long)gridDim.x * blockDim.x;
    for (long long g = (long long)blockIdx.x * blockDim.x + threadIdx.x; g < NG; g += stride) {
        const float* src; long long off;
        if      (g < 2LL*1024*1024) { src = x;  off = g; }
        else if (g < 6LL*1024*1024) { src = wq; off = g - 2LL*1024*1024; }
        else if (g < 7LL*1024*1024) { src = wk; off = g - 6LL*1024*1024; }
        else if (g < 8LL*1024*1024) { src = wv; off = g - 7LL*1024*1024; }
        else                        { src = wo; off = g - 8LL*1024*1024; }
        f32x4 v = *reinterpret_cast<const f32x4*>(src + off * 4);
        u16x4 o;
        o[0] = f2b(v[0]); o[1] = f2b(v[1]); o[2] = f2b(v[2]); o[3] = f2b(v[3]);
        *reinterpret_cast<u16x4*>(dst + g * 4) = o;
    }
}

// ---------------------------------------------------------------------------
// 2) GEMM  C[M x N] = A[M x K] * B^T  (B stored N x K row-major, K = 4096)
//    m97 structure: 128x128 tile, BK=32, double-buffered LDS via global_load_lds,
//    4 waves each computing 64x64 via 16x16x32 bf16 MFMA.
//    B rows selected from up to 3 source matrices (fused QKV).
// ---------------------------------------------------------------------------
template<typename CT>
__global__ __launch_bounds__(256) void gemm_bt(
    const unsigned short* __restrict__ A,
    const unsigned short* __restrict__ B0,
    const unsigned short* __restrict__ B1,
    const unsigned short* __restrict__ B2,
    int nb0, int nb01,          // B-row boundaries: <nb0 -> B0 ; <nb01 -> B1 ; else B2
    CT* __restrict__ C, int ldc)
{
    constexpr int K  = 4096;
    constexpr int BK = 32;
    constexpr int NT = K / BK;
    __shared__ unsigned short As[2][128 * BK];
    __shared__ unsigned short Bs[2][128 * BK];

    const int bm = blockIdx.y, bn = blockIdx.x;
    const int tid = threadIdx.x;
    const int w = tid >> 6, lane = tid & 63;
    const int wr = w >> 1, wc = w & 1;
    const int r16 = lane & 15, g4 = lane >> 4;

    const int bn0 = bn * 128;
    const unsigned short* Bp;
    if      (bn0 < nb0)  Bp = B0 + (size_t)bn0 * K;
    else if (bn0 < nb01) Bp = B1 + (size_t)(bn0 - nb0) * K;
    else                 Bp = B2 + (size_t)(bn0 - nb01) * K;
    const unsigned short* Ap = A + (size_t)bm * 128 * K;

    const int srow = lane >> 2;        // 0..15 (row within 16-row chunk)
    const int scol = (lane & 3) * 8;   // ushort offset within row (4 lanes x 16B = 64B = BK)

    f32x4 acc[4][4] = {};

    auto stage = [&](int buf, int k0) {
        #pragma unroll
        for (int i = 0; i < 2; ++i) {
            const int c = w + i * 4;               // chunk 0..7 (16 rows each)
            const int row = c * 16 + srow;
            gload_lds16(Ap + (size_t)row * K + k0 + scol, &As[buf][c * 16 * BK]);
            gload_lds16(Bp + (size_t)row * K + k0 + scol, &Bs[buf][c * 16 * BK]);
        }
    };

    stage(0, 0);
    asm volatile("s_waitcnt vmcnt(0)" ::: "memory");
    __syncthreads();

    for (int t = 0; t < NT; ++t) {
        const int buf = t & 1;
        if (t + 1 < NT) stage(buf ^ 1, (t + 1) * BK);
        bf16x8 af[4], bfr[4];
        #pragma unroll
        for (int m = 0; m < 4; ++m)
            af[m] = *reinterpret_cast<const bf16x8*>(&As[buf][(wr*64 + m*16 + r16) * BK + g4*8]);
        #pragma unroll
        for (int n = 0; n < 4; ++n)
            bfr[n] = *reinterpret_cast<const bf16x8*>(&Bs[buf][(wc*64 + n*16 + r16) * BK + g4*8]);
        #pragma unroll
        for (int m = 0; m < 4; ++m)
            #pragma unroll
            for (int n = 0; n < 4; ++n)
                acc[m][n] = __builtin_amdgcn_mfma_f32_16x16x32_bf16(af[m], bfr[n], acc[m][n], 0, 0, 0);
        asm volatile("s_waitcnt vmcnt(0)" ::: "memory");
        __syncthreads();
    }

    const size_t crow0 = (size_t)bm * 128 + wr * 64;
    const size_t ccol0 = (size_t)bn * 128 + wc * 64;
    #pragma unroll
    for (int m = 0; m < 4; ++m)
        #pragma unroll
        for (int n = 0; n < 4; ++n)
            #pragma unroll
            for (int r = 0; r < 4; ++r) {
                const size_t row = crow0 + m*16 + g4*4 + r;
                const size_t col = ccol0 + n*16 + r16;
                if constexpr (sizeof(CT) == 2) C[row * ldc + col] = (CT)f2b(acc[m][n][r]);
                else                           C[row * ldc + col] = (CT)acc[m][n][r];
            }
}

// ---------------------------------------------------------------------------
// 3) RoPE in-place on q (cols 0..4096) and k (cols 4096..5120) of qkv buffer.
//    Interleaved pairs (2i, 2i+1), freq index i = (col%128)/2.
// ---------------------------------------------------------------------------
__global__ __launch_bounds__(256) void rope_kernel(unsigned short* __restrict__ qkv,
                                                   const float* __restrict__ fc,
                                                   const float* __restrict__ fs) {
    const int idx = blockIdx.x * 256 + threadIdx.x;   // 2048 rows * 640 groups
    const int s = idx / 640, g = idx - s * 640;
    const int col = g * 8;                            // within first 5120 cols
    unsigned short* p = qkv + (size_t)s * QKVW + col;
    u16x8 v = *reinterpret_cast<const u16x8*>(p);
    const int i0 = (col & 127) >> 1;                  // pair index 0..63 (multiple of 4)
    f32x4 c  = *reinterpret_cast<const f32x4*>(fc + s * 64 + i0);
    f32x4 sn = *reinterpret_cast<const f32x4*>(fs + s * 64 + i0);
    u16x8 o;
    #pragma unroll
    for (int j = 0; j < 4; ++j) {
        float e  = b2f(v[2*j]);
        float od = b2f(v[2*j+1]);
        o[2*j]   = f2b(e * c[j] - od * sn[j]);
        o[2*j+1] = f2b(e * sn[j] + od * c[j]);
    }
    *reinterpret_cast<u16x8*>(p) = o;
}

// ---------------------------------------------------------------------------
// 4) Transpose V part of qkv (cols 5120..6144) into Vt[kvh][128][S2]
// ---------------------------------------------------------------------------
__global__ __launch_bounds__(256) void transpose_v(const unsigned short* __restrict__ qkv,
                                                   unsigned short* __restrict__ Vt) {
    __shared__ unsigned short tile[64][72];           // pad 72: bank-conflict-free column reads
    const int d0g = blockIdx.x * 64;                  // 0..960 within 1024
    const int s0  = blockIdx.y * 64;
    const int kvh = d0g >> 7, dl0 = d0g & 127;
    const int tid = threadIdx.x;
    #pragma unroll
    for (int p = 0; p < 2; ++p) {
        const int sgi = p * 256 + tid;                // 0..511
        const int srow = sgi >> 3, dseg = sgi & 7;
        u16x8 v = *reinterpret_cast<const u16x8*>(
            qkv + (size_t)(s0 + srow) * QKVW + 5120 + d0g + dseg * 8);
        #pragma unroll
        for (int j = 0; j < 8; ++j) tile[srow][dseg * 8 + j] = v[j];
    }
    __syncthreads();
    #pragma unroll
    for (int p = 0; p < 2; ++p) {
        const int sgi = p * 256 + tid;
        const int drow = sgi >> 3, sseg = sgi & 7;
        u16x8 v;
        #pragma unroll
        for (int j = 0; j < 8; ++j) v[j] = tile[sseg * 8 + j][drow];
        *reinterpret_cast<u16x8*>(
            Vt + (size_t)kvh * HD2 * S2 + (size_t)(dl0 + drow) * S2 + s0 + sseg * 8) = v;
    }
}

// ---------------------------------------------------------------------------
// 5) Flash attention. Block = 4 independent waves; each wave owns 16 q rows of
//    one head. KV tiles of 32, causal skip, fp32 online softmax (shfl_xor
//    row-reduce), P -> bf16 via per-wave padded LDS, PV from Vt (contiguous).
// ---------------------------------------------------------------------------
__global__ __launch_bounds__(256) void attn_kernel(const unsigned short* __restrict__ Qkv,
                                                   const unsigned short* __restrict__ Vt,
                                                   unsigned short* __restrict__ O) {
    constexpr float SCALE = 0.08838834764831845f;    // 1/sqrt(128)
    const int h  = blockIdx.y;
    const int qb = blockIdx.x;
    const int w = threadIdx.x >> 6, lane = threadIdx.x & 63;
    const int q0 = qb * 64 + w * 16;
    const int kvh = h >> 2;
    const int r16 = lane & 15, g4 = lane >> 4;

    __shared__ unsigned short Plds[4][16][40];       // per-wave P tile, padded (80B rows)

    // Q fragments (row = q0 + r16, d-slices of 32)
    bf16x8 qf[4];
    const unsigned short* qrow = Qkv + (size_t)(q0 + r16) * QKVW + h * HD2 + g4 * 8;
    #pragma unroll
    for (int f = 0; f < 4; ++f) qf[f] = *reinterpret_cast<const bf16x8*>(qrow + f * 32);

    const unsigned short* Kbase = Qkv + DD + kvh * HD2;       // + kv*QKVW + d
    const unsigned short* Vtb   = Vt + (size_t)kvh * HD2 * S2;

    f32x4 o[8] = {};
    float mr[4] = {-1e30f, -1e30f, -1e30f, -1e30f};
    float lr[4] = {0.f, 0.f, 0.f, 0.f};

    const int ntw = (q0 + 47) >> 5;                  // tiles with kv0 <= q0+15
    for (int t = 0; t < ntw; ++t) {
        const int kv0 = t * 32;
        // QK^T: S[q][kv], rows q from qf (A), cols kv from K (B)
        f32x4 sa[2] = {};
        #pragma unroll
        for (int kb = 0; kb < 2; ++kb) {
            const unsigned short* krow = Kbase + (size_t)(kv0 + kb * 16 + r16) * QKVW + g4 * 8;
            #pragma unroll
            for (int f = 0; f < 4; ++f) {
                bf16x8 kf = *reinterpret_cast<const bf16x8*>(krow + f * 32);
                sa[kb] = __builtin_amdgcn_mfma_f32_16x16x32_bf16(qf[f], kf, sa[kb], 0, 0, 0);
            }
        }
        // scale + causal mask
        const bool needmask = (kv0 + 31 > q0);
        float sv[2][4];
        #pragma unroll
        for (int kb = 0; kb < 2; ++kb)
            #pragma unroll
            for (int r = 0; r < 4; ++r) {
                float xx = sa[kb][r] * SCALE;
                if (needmask) {
                    const int kvg = kv0 + kb * 16 + r16;
                    const int qg  = q0 + g4 * 4 + r;
                    if (kvg > qg) xx = -1e30f;
                }
                sv[kb][r] = xx;
            }
        // row max (across 16 kv lanes)
        float rowm[4];
        #pragma unroll
        for (int r = 0; r < 4; ++r) rowm[r] = fmaxf(sv[0][r], sv[1][r]);
        #pragma unroll
        for (int off = 1; off <= 8; off <<= 1)
            #pragma unroll
            for (int r = 0; r < 4; ++r) rowm[r] = fmaxf(rowm[r], __shfl_xor(rowm[r], off));
        // online softmax update
        float corr[4];
        #pragma unroll
        for (int r = 0; r < 4; ++r) {
            const float mn = fmaxf(mr[r], rowm[r]);
            corr[r] = __expf(mr[r] - mn);
            mr[r] = mn;
        }
        float rs[4] = {0.f, 0.f, 0.f, 0.f};
        #pragma unroll
        for (int kb = 0; kb < 2; ++kb)
            #pragma unroll
            for (int r = 0; r < 4; ++r) {
                const float pp = __expf(sv[kb][r] - mr[r]);
                sv[kb][r] = pp;
                rs[r] += pp;
            }
        #pragma unroll
        for (int off = 1; off <= 8; off <<= 1)
            #pragma unroll
            for (int r = 0; r < 4; ++r) rs[r] += __shfl_xor(rs[r], off);
        #pragma unroll
        for (int r = 0; r < 4; ++r) lr[r] = lr[r] * corr[r] + rs[r];
        #pragma unroll
        for (int n = 0; n < 8; ++n)
            #pragma unroll
            for (int r = 0; r < 4; ++r) o[n][r] *= corr[r];
        // P -> bf16 via LDS (D-layout write, A-fragment read; same-wave only)
        #pragma unroll
        for (int kb = 0; kb < 2; ++kb)
            #pragma unroll
            for (int r = 0; r < 4; ++r)
                Plds[w][g4 * 4 + r][kb * 16 + r16] = f2b(sv[kb][r]);
        asm volatile("s_waitcnt lgkmcnt(0)" ::: "memory");
        const bf16x8 pa = *reinterpret_cast<const bf16x8*>(&Plds[w][r16][g4 * 8]);
        // PV: O[q][d] += P[q][kv] * V[kv][d] ; B-frag from Vt rows (contiguous kv)
        #pragma unroll
        for (int n = 0; n < 8; ++n) {
            const bf16x8 vb = *reinterpret_cast<const bf16x8*>(
                Vtb + (size_t)(n * 16 + r16) * S2 + kv0 + g4 * 8);
            o[n] = __builtin_amdgcn_mfma_f32_16x16x32_bf16(pa, vb, o[n], 0, 0, 0);
        }
    }
    // normalize + write (bf16, (s, h*128+d) layout)
    float inv[4];
    #pragma unroll
    for (int r = 0; r < 4; ++r) inv[r] = 1.0f / lr[r];
    #pragma unroll
    for (int n = 0; n < 8; ++n)
        #pragma unroll
        for (int r = 0; r < 4; ++r)
            O[(size_t)(q0 + g4 * 4 + r) * DD + h * HD2 + n * 16 + r16] = f2b(o[n][r] * inv[r]);
}

// ---------------------------------------------------------------------------
extern "C" void kernel_launch(void* const* d_in, const int* in_sizes, int n_in,
                              void* d_out, int out_size, void* d_ws, size_t ws_size,
                              hipStream_t stream) {
    (void)in_sizes; (void)n_in; (void)out_size; (void)ws_size;
    const float* x  = (const float*)d_in[0];
    const float* wq = (const float*)d_in[1];
    const float* wk = (const float*)d_in[2];
    const float* wv = (const float*)d_in[3];
    const float* wo = (const float*)d_in[4];
    // d_in[5] = mask (causal tril; computed analytically in-kernel)
    const float* fc = (const float*)d_in[6];
    const float* fs = (const float*)d_in[7];
    float* out = (float*)d_out;

    unsigned short* ws = (unsigned short*)d_ws;
    const size_t M1 = 1024 * 1024;
    unsigned short* xb  = ws;              // 8M  (x bf16)    [cvt writes ws[0..48M)]
    unsigned short* wqb = ws + 8  * M1;    // 16M
    unsigned short* wkb = ws + 24 * M1;    // 4M
    unsigned short* wvb = ws + 28 * M1;    // 4M
    unsigned short* wob = ws + 32 * M1;    // 16M
    unsigned short* qkv = ws + 48 * M1;    // 12M (S x 6144)
    unsigned short* vt  = ws + 60 * M1;    // 2M  (KVH x 128 x S)
    unsigned short* ob  = ws + 62 * M1;    // 8M  (S x 4096)
    // total 70M ushorts = 140 MB

    cvt_all<<<2048, 256, 0, stream>>>(x, wq, wk, wv, wo, ws);
    gemm_bt<unsigned short><<<dim3(48, 16), 256, 0, stream>>>(
        xb, wqb, wkb, wvb, 4096, 5120, qkv, QKVW);
    rope_kernel<<<5120, 256, 0, stream>>>(qkv, fc, fs);
    transpose_v<<<dim3(16, 32), 256, 0, stream>>>(qkv, vt);
    attn_kernel<<<dim3(32, 32), 256, 0, stream>>>(qkv, vt, ob);
    gemm_bt<float><<<dim3(32, 16), 256, 0, stream>>>(
        ob, wob, wob, wob, 1 << 30, 1 << 30, out, DD);
}

// Round 2
// 395.376 us; speedup vs baseline: 1.9360x; 1.9360x over previous
//
#include <hip/hip_runtime.h>
#include <hip/hip_bf16.h>
#include <stdint.h>

// Problem constants
#define S2   2048
#define DD   4096
#define NH   32
#define NKVH 8
#define HD2  128
// qkv buffer row width: 4096 (q) + 1024 (k) + 1024 (v)
#define QKVW 6144

typedef __bf16 bf16x8 __attribute__((ext_vector_type(8)));
typedef float  f32x4  __attribute__((ext_vector_type(4)));
typedef unsigned short u16x8 __attribute__((ext_vector_type(8)));
typedef unsigned short u16x4 __attribute__((ext_vector_type(4)));

__device__ __forceinline__ unsigned short f2b(float f) {
    unsigned int u = __builtin_bit_cast(unsigned int, f);
    unsigned int r = (u + 0x7FFFu + ((u >> 16) & 1u)) >> 16;   // RNE
    return (unsigned short)r;
}
__device__ __forceinline__ float b2f(unsigned short h) {
    unsigned int u = ((unsigned int)h) << 16;
    return __builtin_bit_cast(float, u);
}

// global -> LDS direct copy, 16B per lane. LDS dest is wave-uniform base + lane*16.
__device__ __forceinline__ void gload_lds16(const void* g, void* lds) {
    __builtin_amdgcn_global_load_lds(
        (const __attribute__((address_space(1))) void*)(uintptr_t)g,
        (__attribute__((address_space(3))) void*)(uint32_t)(uintptr_t)lds,
        16, 0, 0);
}

// ---------------------------------------------------------------------------
// 1) fp32 -> bf16 conversion for x, wq, wk, wv, wo (concatenated into ws)
// ---------------------------------------------------------------------------
__global__ void cvt_all(const float* __restrict__ x,  const float* __restrict__ wq,
                        const float* __restrict__ wk, const float* __restrict__ wv,
                        const float* __restrict__ wo, unsigned short* __restrict__ dst) {
    const long long NG = 12LL * 1024 * 1024;  // float4 groups
    const long long stride = (long long)gridDim.x * blockDim.x;
    for (long long g = (long long)blockIdx.x * blockDim.x + threadIdx.x; g < NG; g += stride) {
        const float* src; long long off;
        if      (g < 2LL*1024*1024) { src = x;  off = g; }
        else if (g < 6LL*1024*1024) { src = wq; off = g - 2LL*1024*1024; }
        else if (g < 7LL*1024*1024) { src = wk; off = g - 6LL*1024*1024; }
        else if (g < 8LL*1024*1024) { src = wv; off = g - 7LL*1024*1024; }
        else                        { src = wo; off = g - 8LL*1024*1024; }
        f32x4 v = *reinterpret_cast<const f32x4*>(src + off * 4);
        u16x4 o;
        o[0] = f2b(v[0]); o[1] = f2b(v[1]); o[2] = f2b(v[2]); o[3] = f2b(v[3]);
        *reinterpret_cast<u16x4*>(dst + g * 4) = o;
    }
}

// ---------------------------------------------------------------------------
// 2) GEMM  C[M x N] = A[M x K] * B^T  (B stored N x K row-major, K = 4096)
//    m97 structure (unchanged from round 1; known-good).
// ---------------------------------------------------------------------------
template<typename CT>
__global__ __launch_bounds__(256) void gemm_bt(
    const unsigned short* __restrict__ A,
    const unsigned short* __restrict__ B0,
    const unsigned short* __restrict__ B1,
    const unsigned short* __restrict__ B2,
    int nb0, int nb01,
    CT* __restrict__ C, int ldc)
{
    constexpr int K  = 4096;
    constexpr int BK = 32;
    constexpr int NT = K / BK;
    __shared__ unsigned short As[2][128 * BK];
    __shared__ unsigned short Bs[2][128 * BK];

    const int bm = blockIdx.y, bn = blockIdx.x;
    const int tid = threadIdx.x;
    const int w = tid >> 6, lane = tid & 63;
    const int wr = w >> 1, wc = w & 1;
    const int r16 = lane & 15, g4 = lane >> 4;

    const int bn0 = bn * 128;
    const unsigned short* Bp;
    if      (bn0 < nb0)  Bp = B0 + (size_t)bn0 * K;
    else if (bn0 < nb01) Bp = B1 + (size_t)(bn0 - nb0) * K;
    else                 Bp = B2 + (size_t)(bn0 - nb01) * K;
    const unsigned short* Ap = A + (size_t)bm * 128 * K;

    const int srow = lane >> 2;
    const int scol = (lane & 3) * 8;

    f32x4 acc[4][4] = {};

    auto stage = [&](int buf, int k0) {
        #pragma unroll
        for (int i = 0; i < 2; ++i) {
            const int c = w + i * 4;
            const int row = c * 16 + srow;
            gload_lds16(Ap + (size_t)row * K + k0 + scol, &As[buf][c * 16 * BK]);
            gload_lds16(Bp + (size_t)row * K + k0 + scol, &Bs[buf][c * 16 * BK]);
        }
    };

    stage(0, 0);
    asm volatile("s_waitcnt vmcnt(0)" ::: "memory");
    __syncthreads();

    for (int t = 0; t < NT; ++t) {
        const int buf = t & 1;
        if (t + 1 < NT) stage(buf ^ 1, (t + 1) * BK);
        bf16x8 af[4], bfr[4];
        #pragma unroll
        for (int m = 0; m < 4; ++m)
            af[m] = *reinterpret_cast<const bf16x8*>(&As[buf][(wr*64 + m*16 + r16) * BK + g4*8]);
        #pragma unroll
        for (int n = 0; n < 4; ++n)
            bfr[n] = *reinterpret_cast<const bf16x8*>(&Bs[buf][(wc*64 + n*16 + r16) * BK + g4*8]);
        #pragma unroll
        for (int m = 0; m < 4; ++m)
            #pragma unroll
            for (int n = 0; n < 4; ++n)
                acc[m][n] = __builtin_amdgcn_mfma_f32_16x16x32_bf16(af[m], bfr[n], acc[m][n], 0, 0, 0);
        asm volatile("s_waitcnt vmcnt(0)" ::: "memory");
        __syncthreads();
    }

    const size_t crow0 = (size_t)bm * 128 + wr * 64;
    const size_t ccol0 = (size_t)bn * 128 + wc * 64;
    #pragma unroll
    for (int m = 0; m < 4; ++m)
        #pragma unroll
        for (int n = 0; n < 4; ++n)
            #pragma unroll
            for (int r = 0; r < 4; ++r) {
                const size_t row = crow0 + m*16 + g4*4 + r;
                const size_t col = ccol0 + n*16 + r16;
                if constexpr (sizeof(CT) == 2) C[row * ldc + col] = (CT)f2b(acc[m][n][r]);
                else                           C[row * ldc + col] = (CT)acc[m][n][r];
            }
}

// ---------------------------------------------------------------------------
// 3) RoPE in-place on q/k cols of qkv. Q part additionally scaled by 1/sqrt(HD)
//    (folds the attention logit scale into Q; saves 32 muls/tile in attn).
// ---------------------------------------------------------------------------
__global__ __launch_bounds__(256) void rope_kernel(unsigned short* __restrict__ qkv,
                                                   const float* __restrict__ fc,
                                                   const float* __restrict__ fs) {
    constexpr float SCALE = 0.08838834764831845f;    // 1/sqrt(128)
    const int idx = blockIdx.x * 256 + threadIdx.x;   // 2048 rows * 640 groups
    const int s = idx / 640, g = idx - s * 640;
    const int col = g * 8;                            // within first 5120 cols
    unsigned short* p = qkv + (size_t)s * QKVW + col;
    u16x8 v = *reinterpret_cast<const u16x8*>(p);
    const int i0 = (col & 127) >> 1;
    f32x4 c  = *reinterpret_cast<const f32x4*>(fc + s * 64 + i0);
    f32x4 sn = *reinterpret_cast<const f32x4*>(fs + s * 64 + i0);
    const float post = (col < DD) ? SCALE : 1.0f;
    u16x8 o;
    #pragma unroll
    for (int j = 0; j < 4; ++j) {
        float e  = b2f(v[2*j]);
        float od = b2f(v[2*j+1]);
        o[2*j]   = f2b((e * c[j] - od * sn[j]) * post);
        o[2*j+1] = f2b((e * sn[j] + od * c[j]) * post);
    }
    *reinterpret_cast<u16x8*>(p) = o;
}

// ---------------------------------------------------------------------------
// 4) Transpose V part of qkv (cols 5120..6144) into Vt[kvh][128][S2]
// ---------------------------------------------------------------------------
__global__ __launch_bounds__(256) void transpose_v(const unsigned short* __restrict__ qkv,
                                                   unsigned short* __restrict__ Vt) {
    __shared__ unsigned short tile[64][72];
    const int d0g = blockIdx.x * 64;
    const int s0  = blockIdx.y * 64;
    const int kvh = d0g >> 7, dl0 = d0g & 127;
    const int tid = threadIdx.x;
    #pragma unroll
    for (int p = 0; p < 2; ++p) {
        const int sgi = p * 256 + tid;
        const int srow = sgi >> 3, dseg = sgi & 7;
        u16x8 v = *reinterpret_cast<const u16x8*>(
            qkv + (size_t)(s0 + srow) * QKVW + 5120 + d0g + dseg * 8);
        #pragma unroll
        for (int j = 0; j < 8; ++j) tile[srow][dseg * 8 + j] = v[j];
    }
    __syncthreads();
    #pragma unroll
    for (int p = 0; p < 2; ++p) {
        const int sgi = p * 256 + tid;
        const int drow = sgi >> 3, sseg = sgi & 7;
        u16x8 v;
        #pragma unroll
        for (int j = 0; j < 8; ++j) v[j] = tile[sseg * 8 + j][drow];
        *reinterpret_cast<u16x8*>(
            Vt + (size_t)kvh * HD2 * S2 + (size_t)(dl0 + drow) * S2 + s0 + sseg * 8) = v;
    }
}

// ---------------------------------------------------------------------------
// 5) Flash attention v2.
//    Grid (8, 32): blockIdx.x = kvh (XCD-pinned: linear%8 == kvh -> each XCD's
//    L2 holds exactly one kv-head's K+V ~1MB). blockIdx.y: head-in-group (&3)
//    and chunk-pair id (>>2).
//    Block = 4 waves; wave owns 32 q-rows. Block covers a 128-row chunk and
//    processes chunk pair (c, 15-c) sequentially -> uniform 34 tiles/block.
//    K (64x128) and V(128x64, from Vt) double-buffered in LDS via
//    global_load_lds, XOR-chunk-swizzled (pre-swizzled global source +
//    swizzled ds_read). One vmcnt(0)+barrier per tile. Defer-max (THR=8).
// ---------------------------------------------------------------------------
__global__ __launch_bounds__(256) void attn_kernel(const unsigned short* __restrict__ Qkv,
                                                   const unsigned short* __restrict__ Vt,
                                                   unsigned short* __restrict__ O) {
    __shared__ unsigned short Klds[2][64 * 128];
    __shared__ unsigned short Vlds[2][128 * 64];
    __shared__ unsigned short Plds[4][32][72];   // per-wave P tile (rows 144B, 16B-aligned)

    const int kvh = blockIdx.x;                  // 0..7
    const int h   = kvh * 4 + (blockIdx.y & 3);
    const int c0  = blockIdx.y >> 2;             // 0..7
    const int w = threadIdx.x >> 6, lane = threadIdx.x & 63;
    const int r16 = lane & 15, g4 = lane >> 4;

    const unsigned short* Kbase = Qkv + DD + kvh * HD2;      // + kv*QKVW + d
    const unsigned short* Vtb   = Vt + (size_t)kvh * HD2 * S2;

    // staging lane constants
    const int krow_l = lane >> 4;      // row within 4-row segment
    const int kchunk = lane & 15;      // 16B chunk within 256B K row
    const int vd_l   = lane >> 3;      // d within 8-row segment
    const int vchunk = lane & 7;       // 16B chunk within 128B V row

    for (int phase = 0; phase < 2; ++phase) {
        const int c   = phase ? (15 - c0) : c0;
        const int qw  = c * 128 + w * 32;        // wave's first q row
        const int ntB = 2 * c + 2;               // 64-kv tiles this block iterates

        // Q fragments: rows qw + m*16 + r16, k-slices f*32 + g4*8 (pre-scaled in rope)
        bf16x8 qf[2][4];
        #pragma unroll
        for (int m = 0; m < 2; ++m)
            #pragma unroll
            for (int f = 0; f < 4; ++f)
                qf[m][f] = *reinterpret_cast<const bf16x8*>(
                    Qkv + (size_t)(qw + m * 16 + r16) * QKVW + h * HD2 + f * 32 + g4 * 8);

        f32x4 o[2][8] = {};
        float mr[2][4], lr[2][4];
        #pragma unroll
        for (int m = 0; m < 2; ++m)
            #pragma unroll
            for (int r = 0; r < 4; ++r) { mr[m][r] = -3e38f; lr[m][r] = 0.f; }

        auto stage = [&](int buf, int kv0) {
            #pragma unroll
            for (int i = 0; i < 4; ++i) {
                const int seg = i * 4 + w;                     // 0..15
                const int row = seg * 4 + krow_l;              // kv row 0..63
                gload_lds16(Kbase + (size_t)(kv0 + row) * QKVW + ((kchunk ^ (row & 7)) * 8),
                            &Klds[buf][seg * 512]);
            }
            #pragma unroll
            for (int i = 0; i < 4; ++i) {
                const int seg = i * 4 + w;
                const int d = seg * 8 + vd_l;                  // d row 0..127
                gload_lds16(Vtb + (size_t)d * S2 + kv0 + ((vchunk ^ (d & 7)) * 8),
                            &Vlds[buf][seg * 512]);
            }
        };

        stage(0, 0);
        asm volatile("s_waitcnt vmcnt(0)" ::: "memory");
        __syncthreads();

        for (int t = 0; t < ntB; ++t) {
            const int buf = t & 1;
            const int kv0 = t * 64;
            if (t + 1 < ntB) stage(buf ^ 1, (t + 1) * 64);

            if (kv0 <= qw + 31) {                 // causal: this wave needs the tile
                // ---- QK^T: S[q 32][kv 64], A=Q rows, B=K rows (kv = out cols) ----
                f32x4 sa[2][4] = {};
                #pragma unroll
                for (int kb = 0; kb < 4; ++kb) {
                    bf16x8 kf[4];
                    #pragma unroll
                    for (int f = 0; f < 4; ++f)
                        kf[f] = *reinterpret_cast<const bf16x8*>(
                            &Klds[buf][(kb * 16 + r16) * 128 + (((f * 4 + g4) ^ (r16 & 7)) * 8)]);
                    #pragma unroll
                    for (int m = 0; m < 2; ++m)
                        #pragma unroll
                        for (int f = 0; f < 4; ++f)
                            sa[m][kb] = __builtin_amdgcn_mfma_f32_16x16x32_bf16(
                                qf[m][f], kf[f], sa[m][kb], 0, 0, 0);
                }
                // ---- causal mask (logits pre-scaled via Q) ----
                const bool needmask = (kv0 + 63 > qw);
                float sv[2][4][4];
                #pragma unroll
                for (int m = 0; m < 2; ++m)
                    #pragma unroll
                    for (int kb = 0; kb < 4; ++kb)
                        #pragma unroll
                        for (int r = 0; r < 4; ++r) {
                            float xx = sa[m][kb][r];
                            if (needmask) {
                                const int kvg = kv0 + kb * 16 + r16;
                                const int qg  = qw + m * 16 + g4 * 4 + r;
                                xx = (kvg > qg) ? -3e38f : xx;
                            }
                            sv[m][kb][r] = xx;
                        }
                // ---- row max (regs then 16-lane shfl tree) ----
                float rowm[2][4];
                #pragma unroll
                for (int m = 0; m < 2; ++m)
                    #pragma unroll
                    for (int r = 0; r < 4; ++r)
                        rowm[m][r] = fmaxf(fmaxf(sv[m][0][r], sv[m][1][r]),
                                           fmaxf(sv[m][2][r], sv[m][3][r]));
                #pragma unroll
                for (int off = 1; off <= 8; off <<= 1)
                    #pragma unroll
                    for (int m = 0; m < 2; ++m)
                        #pragma unroll
                        for (int r = 0; r < 4; ++r)
                            rowm[m][r] = fmaxf(rowm[m][r], __shfl_xor(rowm[m][r], off));
                // ---- defer-max online softmax (T13, THR=8) ----
                float gmax = -3e38f;
                #pragma unroll
                for (int m = 0; m < 2; ++m)
                    #pragma unroll
                    for (int r = 0; r < 4; ++r)
                        gmax = fmaxf(gmax, rowm[m][r] - mr[m][r]);
                if (!__all(gmax <= 8.0f)) {
                    float corr[2][4];
                    #pragma unroll
                    for (int m = 0; m < 2; ++m)
                        #pragma unroll
                        for (int r = 0; r < 4; ++r) {
                            const float mn = fmaxf(mr[m][r], rowm[m][r]);
                            corr[m][r] = __expf(mr[m][r] - mn);
                            mr[m][r] = mn;
                            lr[m][r] *= corr[m][r];
                        }
                    #pragma unroll
                    for (int m = 0; m < 2; ++m)
                        #pragma unroll
                        for (int n = 0; n < 8; ++n)
                            #pragma unroll
                            for (int r = 0; r < 4; ++r)
                                o[m][n][r] *= corr[m][r];
                }
                // ---- P = exp(S - m), row sums ----
                float rs[2][4] = {};
                #pragma unroll
                for (int m = 0; m < 2; ++m)
                    #pragma unroll
                    for (int kb = 0; kb < 4; ++kb)
                        #pragma unroll
                        for (int r = 0; r < 4; ++r) {
                            const float pp = __expf(sv[m][kb][r] - mr[m][r]);
                            sv[m][kb][r] = pp;
                            rs[m][r] += pp;
                        }
                #pragma unroll
                for (int off = 1; off <= 8; off <<= 1)
                    #pragma unroll
                    for (int m = 0; m < 2; ++m)
                        #pragma unroll
                        for (int r = 0; r < 4; ++r)
                            rs[m][r] += __shfl_xor(rs[m][r], off);
                #pragma unroll
                for (int m = 0; m < 2; ++m)
                    #pragma unroll
                    for (int r = 0; r < 4; ++r)
                        lr[m][r] += rs[m][r];
                // ---- P -> bf16 via per-wave LDS (D-layout write, A-frag read) ----
                #pragma unroll
                for (int m = 0; m < 2; ++m)
                    #pragma unroll
                    for (int kb = 0; kb < 4; ++kb)
                        #pragma unroll
                        for (int r = 0; r < 4; ++r)
                            Plds[w][m * 16 + g4 * 4 + r][kb * 16 + r16] = f2b(sv[m][kb][r]);
                asm volatile("s_waitcnt lgkmcnt(0)" ::: "memory");
                bf16x8 pa[2][2];
                #pragma unroll
                for (int m = 0; m < 2; ++m)
                    #pragma unroll
                    for (int kvs = 0; kvs < 2; ++kvs)
                        pa[m][kvs] = *reinterpret_cast<const bf16x8*>(
                            &Plds[w][m * 16 + r16][kvs * 32 + g4 * 8]);
                // ---- PV: O[q][d] += P[q][kv] * Vt[d][kv] ----
                #pragma unroll
                for (int kvs = 0; kvs < 2; ++kvs)
                    #pragma unroll
                    for (int n = 0; n < 8; ++n) {
                        const bf16x8 vb = *reinterpret_cast<const bf16x8*>(
                            &Vlds[buf][(n * 16 + r16) * 64 + (((kvs * 4 + g4) ^ (r16 & 7)) * 8)]);
                        #pragma unroll
                        for (int m = 0; m < 2; ++m)
                            o[m][n] = __builtin_amdgcn_mfma_f32_16x16x32_bf16(
                                pa[m][kvs], vb, o[m][n], 0, 0, 0);
                    }
            }

            asm volatile("s_waitcnt vmcnt(0)" ::: "memory");
            __syncthreads();
        }

        // ---- normalize + write (bf16, (s, h*128+d)) ----
        float inv[2][4];
        #pragma unroll
        for (int m = 0; m < 2; ++m)
            #pragma unroll
            for (int r = 0; r < 4; ++r) inv[m][r] = 1.0f / lr[m][r];
        #pragma unroll
        for (int m = 0; m < 2; ++m)
            #pragma unroll
            for (int n = 0; n < 8; ++n)
                #pragma unroll
                for (int r = 0; r < 4; ++r)
                    O[(size_t)(qw + m * 16 + g4 * 4 + r) * DD + h * HD2 + n * 16 + r16] =
                        f2b(o[m][n][r] * inv[m][r]);
    }
}

// ---------------------------------------------------------------------------
extern "C" void kernel_launch(void* const* d_in, const int* in_sizes, int n_in,
                              void* d_out, int out_size, void* d_ws, size_t ws_size,
                              hipStream_t stream) {
    (void)in_sizes; (void)n_in; (void)out_size; (void)ws_size;
    const float* x  = (const float*)d_in[0];
    const float* wq = (const float*)d_in[1];
    const float* wk = (const float*)d_in[2];
    const float* wv = (const float*)d_in[3];
    const float* wo = (const float*)d_in[4];
    // d_in[5] = mask (causal tril; computed analytically in-kernel)
    const float* fc = (const float*)d_in[6];
    const float* fs = (const float*)d_in[7];
    float* out = (float*)d_out;

    unsigned short* ws = (unsigned short*)d_ws;
    const size_t M1 = 1024 * 1024;
    unsigned short* xb  = ws;              // 8M  (x bf16)
    unsigned short* wqb = ws + 8  * M1;    // 16M
    unsigned short* wkb = ws + 24 * M1;    // 4M
    unsigned short* wvb = ws + 28 * M1;    // 4M
    unsigned short* wob = ws + 32 * M1;    // 16M
    unsigned short* qkv = ws + 48 * M1;    // 12M (S x 6144)
    unsigned short* vt  = ws + 60 * M1;    // 2M  (KVH x 128 x S)
    unsigned short* ob  = ws + 62 * M1;    // 8M  (S x 4096)

    cvt_all<<<2048, 256, 0, stream>>>(x, wq, wk, wv, wo, ws);
    gemm_bt<unsigned short><<<dim3(48, 16), 256, 0, stream>>>(
        xb, wqb, wkb, wvb, 4096, 5120, qkv, QKVW);
    rope_kernel<<<5120, 256, 0, stream>>>(qkv, fc, fs);
    transpose_v<<<dim3(16, 32), 256, 0, stream>>>(qkv, vt);
    attn_kernel<<<dim3(8, 32), 256, 0, stream>>>(qkv, vt, ob);
    gemm_bt<float><<<dim3(32, 16), 256, 0, stream>>>(
        ob, wob, wob, wob, 1 << 30, 1 << 30, out, DD);
}

// Round 3
// 378.109 us; speedup vs baseline: 2.0244x; 1.0457x over previous
//
#include <hip/hip_runtime.h>
#include <hip/hip_bf16.h>
#include <stdint.h>

// Problem constants
#define S2   2048
#define DD   4096
#define NH   32
#define NKVH 8
#define HD2  128
// qkv buffer row width: 4096 (q) + 1024 (k) + 1024 (v)
#define QKVW 6144

typedef __bf16 bf16x8 __attribute__((ext_vector_type(8)));
typedef float  f32x4  __attribute__((ext_vector_type(4)));
typedef unsigned short u16x8 __attribute__((ext_vector_type(8)));
typedef unsigned short u16x4 __attribute__((ext_vector_type(4)));

__device__ __forceinline__ unsigned short f2b(float f) {
    unsigned int u = __builtin_bit_cast(unsigned int, f);
    unsigned int r = (u + 0x7FFFu + ((u >> 16) & 1u)) >> 16;   // RNE
    return (unsigned short)r;
}
__device__ __forceinline__ float b2f(unsigned short h) {
    unsigned int u = ((unsigned int)h) << 16;
    return __builtin_bit_cast(float, u);
}

// global -> LDS direct copy, 16B per lane. LDS dest is wave-uniform base + lane*16.
__device__ __forceinline__ void gload_lds16(const void* g, void* lds) {
    __builtin_amdgcn_global_load_lds(
        (const __attribute__((address_space(1))) void*)(uintptr_t)g,
        (__attribute__((address_space(3))) void*)(uint32_t)(uintptr_t)lds,
        16, 0, 0);
}

// raw barrier (no vmcnt drain) + compiler memory fences so LDS ops don't cross
#define BAR() do { asm volatile("" ::: "memory"); \
                   __builtin_amdgcn_s_barrier();  \
                   asm volatile("" ::: "memory"); } while (0)
#define WAITV(n) asm volatile("s_waitcnt vmcnt(" #n ")" ::: "memory")

// ---------------------------------------------------------------------------
// 1) fp32 -> bf16 conversion for x, wq, wk, wv, wo (concatenated into ws)
// ---------------------------------------------------------------------------
__global__ void cvt_all(const float* __restrict__ x,  const float* __restrict__ wq,
                        const float* __restrict__ wk, const float* __restrict__ wv,
                        const float* __restrict__ wo, unsigned short* __restrict__ dst) {
    const long long NG = 12LL * 1024 * 1024;  // float4 groups
    const long long stride = (long long)gridDim.x * blockDim.x;
    for (long long g = (long long)blockIdx.x * blockDim.x + threadIdx.x; g < NG; g += stride) {
        const float* src; long long off;
        if      (g < 2LL*1024*1024) { src = x;  off = g; }
        else if (g < 6LL*1024*1024) { src = wq; off = g - 2LL*1024*1024; }
        else if (g < 7LL*1024*1024) { src = wk; off = g - 6LL*1024*1024; }
        else if (g < 8LL*1024*1024) { src = wv; off = g - 7LL*1024*1024; }
        else                        { src = wo; off = g - 8LL*1024*1024; }
        f32x4 v = *reinterpret_cast<const f32x4*>(src + off * 4);
        u16x4 o;
        o[0] = f2b(v[0]); o[1] = f2b(v[1]); o[2] = f2b(v[2]); o[3] = f2b(v[3]);
        *reinterpret_cast<u16x4*>(dst + g * 4) = o;
    }
}

// ---------------------------------------------------------------------------
// 2) GEMM  C[M x N] = A[M x K] * B^T, 256x256 tile, BK=64, 8-phase schedule
//    (T2 st-swizzle + T3/T4 counted vmcnt + T5 setprio). 512 threads = 8 waves
//    (2M x 4N), per-wave 128x64 output, 16 MFMA per phase, 4 phases/K-tile.
//    Stage units = per-phase consumption row-sets:
//      A-half h: LDS rows {wr*128 + h*64 .. +63},  B-half h: {wc*64 + h*32 .. +31}
//    vmcnt ledger (2 loads/wave/unit; stages at ph0(x2),ph1,ph2):
//      end-ph0: vmcnt(6)  -> B-half1(t) landed
//      end-ph1: vmcnt(6)  -> A-half1(t) landed
//      end-ph3: vmcnt(4)  -> A-half0(t+1), B-half0(t+1) landed
//    Last tile peeled: vmcnt(2) / vmcnt(0), no staging.
// ---------------------------------------------------------------------------
template<typename CT>
__global__ __launch_bounds__(512) void gemm256(
    const unsigned short* __restrict__ A,
    const unsigned short* __restrict__ B0,
    const unsigned short* __restrict__ B1,
    const unsigned short* __restrict__ B2,
    int nb0, int nb01,
    CT* __restrict__ C, int ldc)
{
    constexpr int K = 4096, BK = 64, NT = K / BK;
    __shared__ unsigned short As[2][256 * 64];
    __shared__ unsigned short Bs[2][256 * 64];

    const int bm = blockIdx.y, bn = blockIdx.x;
    const int tid = threadIdx.x;
    const int w = tid >> 6, lane = tid & 63;
    const int wr = w >> 2, wc = w & 3;          // 2M x 4N wave grid
    const int r16 = lane & 15, g4 = lane >> 4;

    const int bn0 = bn * 256;
    const unsigned short* Bp;
    if      (bn0 < nb0)  Bp = B0 + (size_t)bn0 * K;
    else if (bn0 < nb01) Bp = B1 + (size_t)(bn0 - nb0) * K;
    else                 Bp = B2 + (size_t)(bn0 - nb01) * K;
    const unsigned short* Ap = A + (size_t)bm * 256 * K;

    // staging lane constants: lane covers (row_in_issue = lane>>3, 16B chunk = lane&7)
    const int lrow = lane >> 3;   // 0..7
    const int lchk = lane & 7;    // 0..7

    f32x4 acc[8][4] = {};
    bf16x8 af[4][2], b0[2][2], b1[2][2];

    // LDS[row][c] holds global chunk (row, c ^ (row&7)); read with same XOR (T2).
    auto stageA = [&](int buf, int tt, int half) {
        #pragma unroll
        for (int i = 0; i < 2; ++i) {
            const int s  = i * 8 + w;                                  // 0..15
            const int rb = ((s & 7) * 8) + ((s >> 3) * 128) + half * 64;
            const int row = rb + lrow;
            gload_lds16(Ap + (size_t)row * K + tt * BK + ((lchk ^ (row & 7)) * 8),
                        &As[buf][rb * 64]);
        }
    };
    auto stageB = [&](int buf, int tt, int half) {
        #pragma unroll
        for (int i = 0; i < 2; ++i) {
            const int s  = i * 8 + w;
            const int rb = ((s & 3) * 8) + ((s >> 2) * 64) + half * 32;
            const int row = rb + lrow;
            gload_lds16(Bp + (size_t)row * K + tt * BK + ((lchk ^ (row & 7)) * 8),
                        &Bs[buf][rb * 64]);
        }
    };
    auto readA = [&](int buf, int mh) {
        #pragma unroll
        for (int m = 0; m < 4; ++m)
            #pragma unroll
            for (int kk = 0; kk < 2; ++kk) {
                const int row = wr * 128 + mh * 64 + m * 16 + r16;
                af[m][kk] = *reinterpret_cast<const bf16x8*>(
                    &As[buf][row * 64 + (((kk * 4 + g4) ^ (row & 7)) * 8)]);
            }
    };
    auto readB = [&](int buf, int nh, bf16x8 (&br)[2][2]) {
        #pragma unroll
        for (int n = 0; n < 2; ++n)
            #pragma unroll
            for (int kk = 0; kk < 2; ++kk) {
                const int row = wc * 64 + nh * 32 + n * 16 + r16;
                br[n][kk] = *reinterpret_cast<const bf16x8*>(
                    &Bs[buf][row * 64 + (((kk * 4 + g4) ^ (row & 7)) * 8)]);
            }
    };
    auto mma = [&](bf16x8 (&br)[2][2], int mh, int nh) {
        __builtin_amdgcn_s_setprio(1);
        #pragma unroll
        for (int m = 0; m < 4; ++m)
            #pragma unroll
            for (int n = 0; n < 2; ++n)
                #pragma unroll
                for (int kk = 0; kk < 2; ++kk)
                    acc[mh * 4 + m][nh * 2 + n] = __builtin_amdgcn_mfma_f32_16x16x32_bf16(
                        af[m][kk], br[n][kk], acc[mh * 4 + m][nh * 2 + n], 0, 0, 0);
        __builtin_amdgcn_s_setprio(0);
    };

    // prologue: stage tile 0 in consumption order; wait for A-half0,B-half0
    stageA(0, 0, 0); stageB(0, 0, 0); stageB(0, 0, 1); stageA(0, 0, 1);
    WAITV(4);
    BAR();

    for (int t = 0; t < NT - 1; ++t) {
        const int buf = t & 1;
        // ---- phase 0: Q(0,0) ----
        readA(buf, 0); readB(buf, 0, b0);
        stageA(buf ^ 1, t + 1, 0); stageB(buf ^ 1, t + 1, 0);
        BAR();
        mma(b0, 0, 0);
        WAITV(6);
        BAR();
        // ---- phase 1: Q(0,1) ----
        readB(buf, 1, b1);
        stageB(buf ^ 1, t + 1, 1);
        BAR();
        mma(b1, 0, 1);
        WAITV(6);
        BAR();
        // ---- phase 2: Q(1,1) ----
        readA(buf, 1);
        stageA(buf ^ 1, t + 1, 1);
        BAR();
        mma(b1, 1, 1);
        BAR();
        // ---- phase 3: Q(1,0) (register-resident operands) ----
        mma(b0, 1, 0);
        WAITV(4);
        BAR();
    }
    // ---- last tile (no staging; peeled vmcnt) ----
    {
        const int buf = (NT - 1) & 1;
        readA(buf, 0); readB(buf, 0, b0);
        BAR();
        mma(b0, 0, 0);
        WAITV(2);
        BAR();
        readB(buf, 1, b1);
        mma(b1, 0, 1);
        WAITV(0);
        readA(buf, 1);
        mma(b1, 1, 1);
        mma(b0, 1, 0);
    }

    // ---- epilogue: C write ----
    const size_t crow0 = (size_t)bm * 256 + wr * 128;
    const size_t ccol0 = (size_t)bn * 256 + wc * 64;
    #pragma unroll
    for (int m = 0; m < 8; ++m)
        #pragma unroll
        for (int n = 0; n < 4; ++n)
            #pragma unroll
            for (int r = 0; r < 4; ++r) {
                const size_t row = crow0 + m * 16 + g4 * 4 + r;
                const size_t col = ccol0 + n * 16 + r16;
                if constexpr (sizeof(CT) == 2) C[row * ldc + col] = (CT)f2b(acc[m][n][r]);
                else                           C[row * ldc + col] = (CT)acc[m][n][r];
            }
}

// ---------------------------------------------------------------------------
// 3) RoPE in-place on q/k cols of qkv. Q part additionally scaled by 1/sqrt(HD).
// ---------------------------------------------------------------------------
__global__ __launch_bounds__(256) void rope_kernel(unsigned short* __restrict__ qkv,
                                                   const float* __restrict__ fc,
                                                   const float* __restrict__ fs) {
    constexpr float SCALE = 0.08838834764831845f;    // 1/sqrt(128)
    const int idx = blockIdx.x * 256 + threadIdx.x;   // 2048 rows * 640 groups
    const int s = idx / 640, g = idx - s * 640;
    const int col = g * 8;                            // within first 5120 cols
    unsigned short* p = qkv + (size_t)s * QKVW + col;
    u16x8 v = *reinterpret_cast<const u16x8*>(p);
    const int i0 = (col & 127) >> 1;
    f32x4 c  = *reinterpret_cast<const f32x4*>(fc + s * 64 + i0);
    f32x4 sn = *reinterpret_cast<const f32x4*>(fs + s * 64 + i0);
    const float post = (col < DD) ? SCALE : 1.0f;
    u16x8 o;
    #pragma unroll
    for (int j = 0; j < 4; ++j) {
        float e  = b2f(v[2*j]);
        float od = b2f(v[2*j+1]);
        o[2*j]   = f2b((e * c[j] - od * sn[j]) * post);
        o[2*j+1] = f2b((e * sn[j] + od * c[j]) * post);
    }
    *reinterpret_cast<u16x8*>(p) = o;
}

// ---------------------------------------------------------------------------
// 4) Transpose V part of qkv (cols 5120..6144) into Vt[kvh][128][S2]
// ---------------------------------------------------------------------------
__global__ __launch_bounds__(256) void transpose_v(const unsigned short* __restrict__ qkv,
                                                   unsigned short* __restrict__ Vt) {
    __shared__ unsigned short tile[64][72];
    const int d0g = blockIdx.x * 64;
    const int s0  = blockIdx.y * 64;
    const int kvh = d0g >> 7, dl0 = d0g & 127;
    const int tid = threadIdx.x;
    #pragma unroll
    for (int p = 0; p < 2; ++p) {
        const int sgi = p * 256 + tid;
        const int srow = sgi >> 3, dseg = sgi & 7;
        u16x8 v = *reinterpret_cast<const u16x8*>(
            qkv + (size_t)(s0 + srow) * QKVW + 5120 + d0g + dseg * 8);
        #pragma unroll
        for (int j = 0; j < 8; ++j) tile[srow][dseg * 8 + j] = v[j];
    }
    __syncthreads();
    #pragma unroll
    for (int p = 0; p < 2; ++p) {
        const int sgi = p * 256 + tid;
        const int drow = sgi >> 3, sseg = sgi & 7;
        u16x8 v;
        #pragma unroll
        for (int j = 0; j < 8; ++j) v[j] = tile[sseg * 8 + j][drow];
        *reinterpret_cast<u16x8*>(
            Vt + (size_t)kvh * HD2 * S2 + (size_t)(dl0 + drow) * S2 + s0 + sseg * 8) = v;
    }
}

// ---------------------------------------------------------------------------
// 5) Flash attention (unchanged from round 2).
// ---------------------------------------------------------------------------
__global__ __launch_bounds__(256) void attn_kernel(const unsigned short* __restrict__ Qkv,
                                                   const unsigned short* __restrict__ Vt,
                                                   unsigned short* __restrict__ O) {
    __shared__ unsigned short Klds[2][64 * 128];
    __shared__ unsigned short Vlds[2][128 * 64];
    __shared__ unsigned short Plds[4][32][72];

    const int kvh = blockIdx.x;                  // 0..7
    const int h   = kvh * 4 + (blockIdx.y & 3);
    const int c0  = blockIdx.y >> 2;             // 0..7
    const int w = threadIdx.x >> 6, lane = threadIdx.x & 63;
    const int r16 = lane & 15, g4 = lane >> 4;

    const unsigned short* Kbase = Qkv + DD + kvh * HD2;
    const unsigned short* Vtb   = Vt + (size_t)kvh * HD2 * S2;

    const int krow_l = lane >> 4;
    const int kchunk = lane & 15;
    const int vd_l   = lane >> 3;
    const int vchunk = lane & 7;

    for (int phase = 0; phase < 2; ++phase) {
        const int c   = phase ? (15 - c0) : c0;
        const int qw  = c * 128 + w * 32;
        const int ntB = 2 * c + 2;

        bf16x8 qf[2][4];
        #pragma unroll
        for (int m = 0; m < 2; ++m)
            #pragma unroll
            for (int f = 0; f < 4; ++f)
                qf[m][f] = *reinterpret_cast<const bf16x8*>(
                    Qkv + (size_t)(qw + m * 16 + r16) * QKVW + h * HD2 + f * 32 + g4 * 8);

        f32x4 o[2][8] = {};
        float mr[2][4], lr[2][4];
        #pragma unroll
        for (int m = 0; m < 2; ++m)
            #pragma unroll
            for (int r = 0; r < 4; ++r) { mr[m][r] = -3e38f; lr[m][r] = 0.f; }

        auto stage = [&](int buf, int kv0) {
            #pragma unroll
            for (int i = 0; i < 4; ++i) {
                const int seg = i * 4 + w;
                const int row = seg * 4 + krow_l;
                gload_lds16(Kbase + (size_t)(kv0 + row) * QKVW + ((kchunk ^ (row & 7)) * 8),
                            &Klds[buf][seg * 512]);
            }
            #pragma unroll
            for (int i = 0; i < 4; ++i) {
                const int seg = i * 4 + w;
                const int d = seg * 8 + vd_l;
                gload_lds16(Vtb + (size_t)d * S2 + kv0 + ((vchunk ^ (d & 7)) * 8),
                            &Vlds[buf][seg * 512]);
            }
        };

        stage(0, 0);
        asm volatile("s_waitcnt vmcnt(0)" ::: "memory");
        __syncthreads();

        for (int t = 0; t < ntB; ++t) {
            const int buf = t & 1;
            const int kv0 = t * 64;
            if (t + 1 < ntB) stage(buf ^ 1, (t + 1) * 64);

            if (kv0 <= qw + 31) {
                f32x4 sa[2][4] = {};
                #pragma unroll
                for (int kb = 0; kb < 4; ++kb) {
                    bf16x8 kf[4];
                    #pragma unroll
                    for (int f = 0; f < 4; ++f)
                        kf[f] = *reinterpret_cast<const bf16x8*>(
                            &Klds[buf][(kb * 16 + r16) * 128 + (((f * 4 + g4) ^ (r16 & 7)) * 8)]);
                    #pragma unroll
                    for (int m = 0; m < 2; ++m)
                        #pragma unroll
                        for (int f = 0; f < 4; ++f)
                            sa[m][kb] = __builtin_amdgcn_mfma_f32_16x16x32_bf16(
                                qf[m][f], kf[f], sa[m][kb], 0, 0, 0);
                }
                const bool needmask = (kv0 + 63 > qw);
                float sv[2][4][4];
                #pragma unroll
                for (int m = 0; m < 2; ++m)
                    #pragma unroll
                    for (int kb = 0; kb < 4; ++kb)
                        #pragma unroll
                        for (int r = 0; r < 4; ++r) {
                            float xx = sa[m][kb][r];
                            if (needmask) {
                                const int kvg = kv0 + kb * 16 + r16;
                                const int qg  = qw + m * 16 + g4 * 4 + r;
                                xx = (kvg > qg) ? -3e38f : xx;
                            }
                            sv[m][kb][r] = xx;
                        }
                float rowm[2][4];
                #pragma unroll
                for (int m = 0; m < 2; ++m)
                    #pragma unroll
                    for (int r = 0; r < 4; ++r)
                        rowm[m][r] = fmaxf(fmaxf(sv[m][0][r], sv[m][1][r]),
                                           fmaxf(sv[m][2][r], sv[m][3][r]));
                #pragma unroll
                for (int off = 1; off <= 8; off <<= 1)
                    #pragma unroll
                    for (int m = 0; m < 2; ++m)
                        #pragma unroll
                        for (int r = 0; r < 4; ++r)
                            rowm[m][r] = fmaxf(rowm[m][r], __shfl_xor(rowm[m][r], off));
                float gmax = -3e38f;
                #pragma unroll
                for (int m = 0; m < 2; ++m)
                    #pragma unroll
                    for (int r = 0; r < 4; ++r)
                        gmax = fmaxf(gmax, rowm[m][r] - mr[m][r]);
                if (!__all(gmax <= 8.0f)) {
                    float corr[2][4];
                    #pragma unroll
                    for (int m = 0; m < 2; ++m)
                        #pragma unroll
                        for (int r = 0; r < 4; ++r) {
                            const float mn = fmaxf(mr[m][r], rowm[m][r]);
                            corr[m][r] = __expf(mr[m][r] - mn);
                            mr[m][r] = mn;
                            lr[m][r] *= corr[m][r];
                        }
                    #pragma unroll
                    for (int m = 0; m < 2; ++m)
                        #pragma unroll
                        for (int n = 0; n < 8; ++n)
                            #pragma unroll
                            for (int r = 0; r < 4; ++r)
                                o[m][n][r] *= corr[m][r];
                }
                float rs[2][4] = {};
                #pragma unroll
                for (int m = 0; m < 2; ++m)
                    #pragma unroll
                    for (int kb = 0; kb < 4; ++kb)
                        #pragma unroll
                        for (int r = 0; r < 4; ++r) {
                            const float pp = __expf(sv[m][kb][r] - mr[m][r]);
                            sv[m][kb][r] = pp;
                            rs[m][r] += pp;
                        }
                #pragma unroll
                for (int off = 1; off <= 8; off <<= 1)
                    #pragma unroll
                    for (int m = 0; m < 2; ++m)
                        #pragma unroll
                        for (int r = 0; r < 4; ++r)
                            rs[m][r] += __shfl_xor(rs[m][r], off);
                #pragma unroll
                for (int m = 0; m < 2; ++m)
                    #pragma unroll
                    for (int r = 0; r < 4; ++r)
                        lr[m][r] += rs[m][r];
                #pragma unroll
                for (int m = 0; m < 2; ++m)
                    #pragma unroll
                    for (int kb = 0; kb < 4; ++kb)
                        #pragma unroll
                        for (int r = 0; r < 4; ++r)
                            Plds[w][m * 16 + g4 * 4 + r][kb * 16 + r16] = f2b(sv[m][kb][r]);
                asm volatile("s_waitcnt lgkmcnt(0)" ::: "memory");
                bf16x8 pa[2][2];
                #pragma unroll
                for (int m = 0; m < 2; ++m)
                    #pragma unroll
                    for (int kvs = 0; kvs < 2; ++kvs)
                        pa[m][kvs] = *reinterpret_cast<const bf16x8*>(
                            &Plds[w][m * 16 + r16][kvs * 32 + g4 * 8]);
                #pragma unroll
                for (int kvs = 0; kvs < 2; ++kvs)
                    #pragma unroll
                    for (int n = 0; n < 8; ++n) {
                        const bf16x8 vb = *reinterpret_cast<const bf16x8*>(
                            &Vlds[buf][(n * 16 + r16) * 64 + (((kvs * 4 + g4) ^ (r16 & 7)) * 8)]);
                        #pragma unroll
                        for (int m = 0; m < 2; ++m)
                            o[m][n] = __builtin_amdgcn_mfma_f32_16x16x32_bf16(
                                pa[m][kvs], vb, o[m][n], 0, 0, 0);
                    }
            }

            asm volatile("s_waitcnt vmcnt(0)" ::: "memory");
            __syncthreads();
        }

        float inv[2][4];
        #pragma unroll
        for (int m = 0; m < 2; ++m)
            #pragma unroll
            for (int r = 0; r < 4; ++r) inv[m][r] = 1.0f / lr[m][r];
        #pragma unroll
        for (int m = 0; m < 2; ++m)
            #pragma unroll
            for (int n = 0; n < 8; ++n)
                #pragma unroll
                for (int r = 0; r < 4; ++r)
                    O[(size_t)(qw + m * 16 + g4 * 4 + r) * DD + h * HD2 + n * 16 + r16] =
                        f2b(o[m][n][r] * inv[m][r]);
    }
}

// ---------------------------------------------------------------------------
extern "C" void kernel_launch(void* const* d_in, const int* in_sizes, int n_in,
                              void* d_out, int out_size, void* d_ws, size_t ws_size,
                              hipStream_t stream) {
    (void)in_sizes; (void)n_in; (void)out_size; (void)ws_size;
    const float* x  = (const float*)d_in[0];
    const float* wq = (const float*)d_in[1];
    const float* wk = (const float*)d_in[2];
    const float* wv = (const float*)d_in[3];
    const float* wo = (const float*)d_in[4];
    // d_in[5] = mask (causal tril; computed analytically in-kernel)
    const float* fc = (const float*)d_in[6];
    const float* fs = (const float*)d_in[7];
    float* out = (float*)d_out;

    unsigned short* ws = (unsigned short*)d_ws;
    const size_t M1 = 1024 * 1024;
    unsigned short* xb  = ws;              // 8M  (x bf16)
    unsigned short* wqb = ws + 8  * M1;    // 16M
    unsigned short* wkb = ws + 24 * M1;    // 4M
    unsigned short* wvb = ws + 28 * M1;    // 4M
    unsigned short* wob = ws + 32 * M1;    // 16M
    unsigned short* qkv = ws + 48 * M1;    // 12M (S x 6144)
    unsigned short* vt  = ws + 60 * M1;    // 2M  (KVH x 128 x S)
    unsigned short* ob  = ws + 62 * M1;    // 8M  (S x 4096)

    cvt_all<<<2048, 256, 0, stream>>>(x, wq, wk, wv, wo, ws);
    gemm256<unsigned short><<<dim3(24, 8), 512, 0, stream>>>(
        xb, wqb, wkb, wvb, 4096, 5120, qkv, QKVW);
    rope_kernel<<<5120, 256, 0, stream>>>(qkv, fc, fs);
    transpose_v<<<dim3(16, 32), 256, 0, stream>>>(qkv, vt);
    attn_kernel<<<dim3(8, 32), 256, 0, stream>>>(qkv, vt, ob);
    gemm256<float><<<dim3(16, 8), 512, 0, stream>>>(
        ob, wob, wob, wob, 1 << 30, 1 << 30, out, DD);
}